// Round 8
// baseline (70.077 us; speedup 1.0000x reference)
//
#include <hip/hip_runtime.h>
#include <hip/hip_bf16.h>

typedef __attribute__((ext_vector_type(8))) short bf16x8;
typedef __attribute__((ext_vector_type(4))) float f32x4;
typedef __attribute__((ext_vector_type(8))) unsigned short u16x8;

#define KD 2304
#define PL 4232                      // padded plane stride (elems), multiple of 8
#define OUT_PER_B (256 * 1024)

static __device__ __forceinline__ ushort f2bf(float f) {
  union { float f; unsigned int i; } v; v.f = f;
  unsigned int x = v.i;
  x += 0x7fffu + ((x >> 16) & 1u);   // round-to-nearest-even
  return (ushort)(x >> 16);
}

#define GLDS16(gp, lp)                                                         \
  __builtin_amdgcn_global_load_lds(                                            \
      (const __attribute__((address_space(1))) void*)(gp),                     \
      (__attribute__((address_space(3))) void*)(lp), 16, 0, 0)

#define LDSOFF(p) ((unsigned)(size_t)(__attribute__((address_space(3))) const void*)(p))

// naked ds_read: NO memory clobber -> compiler inserts no vmcnt before it
#define DSREAD(dst, addr) \
  asm volatile("ds_read_b128 %0, %1" : "=v"(dst) : "v"(addr))

// ---------------- Kernel 1: separable 4x4 FIR + weight cast ---------------------
__global__ __launch_bounds__(256) void k_fir(const float* __restrict__ x,
                                             ushort* __restrict__ xfn,
                                             const float* __restrict__ w,
                                             ushort* __restrict__ wb) {
  __shared__ float sxp[64 * 76];   // row r at cols 4..67; cols 2,3,68,69 zero halo
  __shared__ float stp[68 * 68];   // h-row i' at row i'+2; rows 0,1,66,67 zero
  const int plane = blockIdx.x;               // 0..4095
  const float* xp = x + (size_t)plane * 4096;
  ushort* op = xfn + (size_t)plane * PL;
  const int t = threadIdx.x;

  if (plane < 2304) {              // fused weight cast
    int iw = plane * 256 + t;
    float v = w[iw];
    int j = iw % 9;
    int t2 = iw / 9;
    int ic = t2 & 255;
    int oc = t2 >> 8;
    wb[oc * KD + j * 256 + ic] = f2bf(v);
  }

  {
    int r = t & 63, cs = t >> 6;
    int col = (cs < 2) ? (2 + cs) : (66 + cs);   // 2,3,68,69
    sxp[r * 76 + col] = 0.f;
  }
  for (int i = t; i < 272; i += 256) {           // 4 rows x 68
    int rr = i / 68, cc = i - rr * 68;
    int row = (rr < 2) ? rr : (64 + rr);         // 0,1,66,67
    stp[row * 68 + cc] = 0.f;
  }

  const float4* x4 = (const float4*)xp;
#pragma unroll
  for (int i = 0; i < 4; ++i) {
    int f4 = t + 256 * i;
    int r = f4 >> 4, w4 = f4 & 15;
    *(float4*)&sxp[r * 76 + 4 + w4 * 4] = x4[f4];
  }
  __syncthreads();

  for (int g = t; g < 1088; g += 256) {
    int i = g / 17, jg = g - i * 17;
    int j0 = jg << 2;
    const float* s = &sxp[i * 76 + j0];
    float4 a0 = *(const float4*)(s);
    float4 a1 = *(const float4*)(s + 4);
    float4 a2 = *(const float4*)(s + 8);
    float4 o;
    o.x = (a0.z + a1.y) + 3.f * (a0.w + a1.x);
    o.y = (a0.w + a1.z) + 3.f * (a1.x + a1.y);
    o.z = (a1.x + a1.w) + 3.f * (a1.y + a1.z);
    o.w = (a1.y + a2.x) + 3.f * (a1.z + a1.w);
    *(float4*)&stp[(i + 2) * 68 + j0] = o;
  }
  __syncthreads();

  for (int g = t; g < 1105; g += 256) {
    int i = g / 17, jg = g - i * 17;
    int j0 = jg << 2;
    const float* s = &stp[i * 68 + j0];
    float4 r0 = *(const float4*)(s);
    float4 r1 = *(const float4*)(s + 68);
    float4 r2 = *(const float4*)(s + 136);
    float4 r3 = *(const float4*)(s + 204);
    float4 o;
    o.x = (r0.x + r3.x) + 3.f * (r1.x + r2.x);
    o.y = (r0.y + r3.y) + 3.f * (r1.y + r2.y);
    o.z = (r0.z + r3.z) + 3.f * (r1.z + r2.z);
    o.w = (r0.w + r3.w) + 3.f * (r1.w + r2.w);
    ushort* q = op + i * 65 + j0;
    q[0] = f2bf(o.x * 0.015625f);
    if (j0 + 1 < 65) q[1] = f2bf(o.y * 0.015625f);
    if (j0 + 2 < 65) q[2] = f2bf(o.z * 0.015625f);
    if (j0 + 3 < 65) q[3] = f2bf(o.w * 0.015625f);
  }
}

// ---------------- Kernel 2: transpose NCHW -> NHWC (bf16), 16B both sides -------
__global__ __launch_bounds__(256) void k_tr(const ushort* __restrict__ xfn,
                                            ushort* __restrict__ xft) {
  __shared__ ushort ld[128 * 66];
  const int hw0 = blockIdx.x * 128;
  const int c0 = blockIdx.y * 64;
  const int b = blockIdx.z;
  const int t = threadIdx.x;

#pragma unroll
  for (int it = 0; it < 4; ++it) {
    int idx = it * 256 + t;                 // 0..1023
    int c = idx >> 4, q = idx & 15;
    u16x8 v = {};
    if (hw0 + q * 8 < 4225)
      v = *(const u16x8*)(xfn + (size_t)(b * 256 + c0 + c) * PL + hw0 + q * 8);
#pragma unroll
    for (int k = 0; k < 8; ++k)
      ld[(q * 8 + k) * 66 + (c ^ (k << 3))] = v[k];
  }
  __syncthreads();
#pragma unroll
  for (int it = 0; it < 4; ++it) {
    int idx = it * 256 + t;
    int hwl = idx >> 3, a = idx & 7;
    int k7 = hwl & 7;
    int hw = hw0 + hwl;
    if (hw < 4225) {
      u16x8 v = *(const u16x8*)&ld[hwl * 66 + ((a ^ k7) << 3)];
      *(u16x8*)&xft[((size_t)(b * 4225 + hw) << 8) + c0 + (a << 3)] = v;
    }
  }
}

// ---------------- Kernel 3: implicit-conv GEMM, double-buffered counted-vmcnt ---
// C[oc=256][n=16384]; BM=128, BN=64, BK=64; 256 thr (4 waves 2m x 2n, 64x32 each)
// 36 K-iters; STAGE(next) stays in flight across barriers (vmcnt(6), never 0
// in-loop); ds_read via naked asm so the compiler emits no vmcnt(0) drain.
__global__ __launch_bounds__(256) void k_gemm3(const ushort* __restrict__ Wb,
                                               const ushort* __restrict__ Xt,
                                               const float* __restrict__ bias,
                                               float* __restrict__ out) {
  __shared__ ushort lA[2][128 * 64];               // 16 KB each
  __shared__ ushort lB[2][64 * 64];                // 8 KB each  (48 KB total)
  const int bid = blockIdx.x;                      // 0..511
  const int work = (bid & 7) * 64 + (bid >> 3);    // XCD-chunked bijective
  const int ntile = work >> 1;
  const int mtile = work & 1;
  const int m0 = mtile * 128;
  const int n0 = ntile * 64;
  const int t = threadIdx.x;
  const int wid = t >> 6, lane = t & 63;
  const int wm = wid >> 1, wn = wid & 1;
  const int lrow = lane & 15, kgrp = lane >> 4;

  // staging sources (pre-swizzled: lds 16B-chunk (idx&7) holds data chunk (idx&7)^(row&7))
  const ushort* aB[4];
#pragma unroll
  for (int i = 0; i < 4; ++i) {
    int idx = i * 256 + t;
    int row = idx >> 3;
    aB[i] = Wb + (size_t)(m0 + row) * KD + (((idx & 7) ^ (row & 7)) << 3);
  }
  const ushort* bB[2];
#pragma unroll
  for (int i = 0; i < 2; ++i) {
    int idx = i * 256 + t;
    int row = idx >> 3;
    int n = n0 + row;
    int b = n >> 10, oh = (n >> 5) & 31, ow = n & 31;
    bB[i] = Xt + ((size_t)((b * 65 + 2 * oh) * 65 + 2 * ow) << 8) +
            (((idx & 7) ^ (row & 7)) << 3);
  }

#define STAGE(buf, kt)                                                         \
  {                                                                            \
    const int j_ = (kt) >> 2;                                                  \
    const int dh_ = j_ / 3, dw_ = j_ - 3 * dh_;                                \
    const int boff_ = (dh_ * 65 + dw_) * 256 + (((kt) & 3) << 6);              \
    const int k0_ = (kt) << 6;                                                 \
    _Pragma("unroll") for (int i_ = 0; i_ < 4; ++i_)                           \
        GLDS16(aB[i_] + k0_, &lA[buf][(i_ * 256 + t) * 8]);                    \
    _Pragma("unroll") for (int i_ = 0; i_ < 2; ++i_)                           \
        GLDS16(bB[i_] + boff_, &lB[buf][(i_ * 256 + t) * 8]);                  \
  }

  // precomputed swizzled read addresses (LDS byte offsets), buf0
  unsigned aAddr[2][4], bAddr[2][2];
#pragma unroll
  for (int f = 0; f < 4; ++f) {
    int row = wm * 64 + f * 16 + lrow;
#pragma unroll
    for (int s = 0; s < 2; ++s) {
      int col = ((s * 4 + kgrp) ^ row) & 7;
      aAddr[s][f] = LDSOFF(&lA[0][row * 64 + col * 8]);
    }
  }
#pragma unroll
  for (int f = 0; f < 2; ++f) {
    int row = wn * 32 + f * 16 + lrow;
#pragma unroll
    for (int s = 0; s < 2; ++s) {
      int col = ((s * 4 + kgrp) ^ row) & 7;
      bAddr[s][f] = LDSOFF(&lB[0][row * 64 + col * 8]);
    }
  }

  f32x4 acc[4][2];
#pragma unroll
  for (int i = 0; i < 4; ++i)
#pragma unroll
    for (int j = 0; j < 2; ++j) acc[i][j] = (f32x4){0.f, 0.f, 0.f, 0.f};

  STAGE(0, 0);

  for (int kt = 0; kt < 36; ++kt) {
    const int cur = kt & 1;
    if (kt < 35) STAGE(cur ^ 1, kt + 1);

    if (kt < 35)
      asm volatile("s_waitcnt vmcnt(6)" ::: "memory");   // cur tile resident
    else
      asm volatile("s_waitcnt vmcnt(0)" ::: "memory");
    __builtin_amdgcn_s_barrier();
    __builtin_amdgcn_sched_barrier(0);

    const unsigned oA = cur ? (unsigned)(128 * 64 * 2) : 0u;
    const unsigned oB = cur ? (unsigned)(64 * 64 * 2) : 0u;
#pragma unroll
    for (int s = 0; s < 2; ++s) {
      bf16x8 Af0, Af1, Af2, Af3, Bf0, Bf1;
      DSREAD(Af0, aAddr[s][0] + oA);
      DSREAD(Af1, aAddr[s][1] + oA);
      DSREAD(Af2, aAddr[s][2] + oA);
      DSREAD(Af3, aAddr[s][3] + oA);
      DSREAD(Bf0, bAddr[s][0] + oB);
      DSREAD(Bf1, bAddr[s][1] + oB);
      asm volatile("s_waitcnt lgkmcnt(0)" ::: "memory");
      __builtin_amdgcn_sched_barrier(0);
      acc[0][0] = __builtin_amdgcn_mfma_f32_16x16x32_bf16(Af0, Bf0, acc[0][0], 0, 0, 0);
      acc[0][1] = __builtin_amdgcn_mfma_f32_16x16x32_bf16(Af0, Bf1, acc[0][1], 0, 0, 0);
      acc[1][0] = __builtin_amdgcn_mfma_f32_16x16x32_bf16(Af1, Bf0, acc[1][0], 0, 0, 0);
      acc[1][1] = __builtin_amdgcn_mfma_f32_16x16x32_bf16(Af1, Bf1, acc[1][1], 0, 0, 0);
      acc[2][0] = __builtin_amdgcn_mfma_f32_16x16x32_bf16(Af2, Bf0, acc[2][0], 0, 0, 0);
      acc[2][1] = __builtin_amdgcn_mfma_f32_16x16x32_bf16(Af2, Bf1, acc[2][1], 0, 0, 0);
      acc[3][0] = __builtin_amdgcn_mfma_f32_16x16x32_bf16(Af3, Bf0, acc[3][0], 0, 0, 0);
      acc[3][1] = __builtin_amdgcn_mfma_f32_16x16x32_bf16(Af3, Bf1, acc[3][1], 0, 0, 0);
    }
    __builtin_amdgcn_sched_barrier(0);
    __builtin_amdgcn_s_barrier();     // all waves done reading cur before it is re-staged
  }

  f32x4 bv[4];
#pragma unroll
  for (int fm = 0; fm < 4; ++fm)
    bv[fm] = *(const f32x4*)(bias + m0 + wm * 64 + fm * 16 + kgrp * 4);

#pragma unroll
  for (int fm = 0; fm < 4; ++fm) {
#pragma unroll
    for (int fn = 0; fn < 2; ++fn) {
      int nn = n0 + wn * 32 + fn * 16 + lrow;
      int oc = m0 + wm * 64 + fm * 16 + kgrp * 4;
      float* op = out + (size_t)(nn >> 10) * OUT_PER_B + (nn & 1023) +
                  (size_t)oc * 1024;
      op[0]    = acc[fm][fn][0] + bv[fm][0];
      op[1024] = acc[fm][fn][1] + bv[fm][1];
      op[2048] = acc[fm][fn][2] + bv[fm][2];
      op[3072] = acc[fm][fn][3] + bv[fm][3];
    }
  }
}

extern "C" void kernel_launch(void* const* d_in, const int* in_sizes, int n_in,
                              void* d_out, int out_size, void* d_ws, size_t ws_size,
                              hipStream_t stream) {
  const float* x    = (const float*)d_in[0];  // [16,256,64,64]
  const float* w    = (const float*)d_in[1];  // [256,256,3,3]
  const float* bias = (const float*)d_in[2];  // [256]
  float* out = (float*)d_out;                 // [16,256,32,32]

  char* ws = (char*)d_ws;
  ushort* xfn = (ushort*)ws;                        // 4096*4232*2 = 34,668,544 B
  ushort* xft = (ushort*)(ws + 34668544);           // 16*4225*256*2 = 34,611,200 B
  ushort* wb  = (ushort*)(ws + 34668544 + 34611200);// 1,179,648 B

  k_fir<<<4096, 256, 0, stream>>>(x, xfn, w, wb);
  k_tr<<<dim3(34, 4, 16), 256, 0, stream>>>(xfn, xft);
  k_gemm3<<<512, 256, 0, stream>>>(wb, xft, bias, out);
}

// Round 9
// 69.360 us; speedup vs baseline: 1.0103x; 1.0103x over previous
//
#include <hip/hip_runtime.h>
#include <hip/hip_bf16.h>

typedef __attribute__((ext_vector_type(8))) short bf16x8;
typedef __attribute__((ext_vector_type(4))) float f32x4;
typedef __attribute__((ext_vector_type(8))) unsigned short u16x8;

#define KD 2304
#define PL 4232                      // padded plane stride (elems), multiple of 8
#define OUT_PER_B (256 * 1024)

static __device__ __forceinline__ ushort f2bf(float f) {
  union { float f; unsigned int i; } v; v.f = f;
  unsigned int x = v.i;
  x += 0x7fffu + ((x >> 16) & 1u);   // round-to-nearest-even
  return (ushort)(x >> 16);
}

#define GLDS16(gp, lp)                                                         \
  __builtin_amdgcn_global_load_lds(                                            \
      (const __attribute__((address_space(1))) void*)(gp),                     \
      (__attribute__((address_space(3))) void*)(lp), 16, 0, 0)

#define LDSOFF(p) ((unsigned)(size_t)(__attribute__((address_space(3))) const void*)(p))

// naked ds_read: NO memory clobber -> compiler inserts no vmcnt before it
#define DSREAD(dst, addr) \
  asm volatile("ds_read_b128 %0, %1" : "=v"(dst) : "v"(addr))

// ---------------- Kernel 1: separable 4x4 FIR + weight cast ---------------------
__global__ __launch_bounds__(256) void k_fir(const float* __restrict__ x,
                                             ushort* __restrict__ xfn,
                                             const float* __restrict__ w,
                                             ushort* __restrict__ wb) {
  __shared__ float sxp[64 * 76];   // row r at cols 4..67; cols 2,3,68,69 zero halo
  __shared__ float stp[68 * 68];   // h-row i' at row i'+2; rows 0,1,66,67 zero
  const int plane = blockIdx.x;               // 0..4095
  const float* xp = x + (size_t)plane * 4096;
  ushort* op = xfn + (size_t)plane * PL;
  const int t = threadIdx.x;

  if (plane < 2304) {              // fused weight cast
    int iw = plane * 256 + t;
    float v = w[iw];
    int j = iw % 9;
    int t2 = iw / 9;
    int ic = t2 & 255;
    int oc = t2 >> 8;
    wb[oc * KD + j * 256 + ic] = f2bf(v);
  }

  {
    int r = t & 63, cs = t >> 6;
    int col = (cs < 2) ? (2 + cs) : (66 + cs);   // 2,3,68,69
    sxp[r * 76 + col] = 0.f;
  }
  for (int i = t; i < 272; i += 256) {           // 4 rows x 68
    int rr = i / 68, cc = i - rr * 68;
    int row = (rr < 2) ? rr : (64 + rr);         // 0,1,66,67
    stp[row * 68 + cc] = 0.f;
  }

  const float4* x4 = (const float4*)xp;
#pragma unroll
  for (int i = 0; i < 4; ++i) {
    int f4 = t + 256 * i;
    int r = f4 >> 4, w4 = f4 & 15;
    *(float4*)&sxp[r * 76 + 4 + w4 * 4] = x4[f4];
  }
  __syncthreads();

  for (int g = t; g < 1088; g += 256) {
    int i = g / 17, jg = g - i * 17;
    int j0 = jg << 2;
    const float* s = &sxp[i * 76 + j0];
    float4 a0 = *(const float4*)(s);
    float4 a1 = *(const float4*)(s + 4);
    float4 a2 = *(const float4*)(s + 8);
    float4 o;
    o.x = (a0.z + a1.y) + 3.f * (a0.w + a1.x);
    o.y = (a0.w + a1.z) + 3.f * (a1.x + a1.y);
    o.z = (a1.x + a1.w) + 3.f * (a1.y + a1.z);
    o.w = (a1.y + a2.x) + 3.f * (a1.z + a1.w);
    *(float4*)&stp[(i + 2) * 68 + j0] = o;
  }
  __syncthreads();

  for (int g = t; g < 1105; g += 256) {
    int i = g / 17, jg = g - i * 17;
    int j0 = jg << 2;
    const float* s = &stp[i * 68 + j0];
    float4 r0 = *(const float4*)(s);
    float4 r1 = *(const float4*)(s + 68);
    float4 r2 = *(const float4*)(s + 136);
    float4 r3 = *(const float4*)(s + 204);
    float4 o;
    o.x = (r0.x + r3.x) + 3.f * (r1.x + r2.x);
    o.y = (r0.y + r3.y) + 3.f * (r1.y + r2.y);
    o.z = (r0.z + r3.z) + 3.f * (r1.z + r2.z);
    o.w = (r0.w + r3.w) + 3.f * (r1.w + r2.w);
    ushort* q = op + i * 65 + j0;
    q[0] = f2bf(o.x * 0.015625f);
    if (j0 + 1 < 65) q[1] = f2bf(o.y * 0.015625f);
    if (j0 + 2 < 65) q[2] = f2bf(o.z * 0.015625f);
    if (j0 + 3 < 65) q[3] = f2bf(o.w * 0.015625f);
  }
}

// ---------------- Kernel 2: transpose NCHW -> NHWC (bf16), 16B both sides -------
__global__ __launch_bounds__(256) void k_tr(const ushort* __restrict__ xfn,
                                            ushort* __restrict__ xft) {
  __shared__ ushort ld[128 * 66];
  const int hw0 = blockIdx.x * 128;
  const int c0 = blockIdx.y * 64;
  const int b = blockIdx.z;
  const int t = threadIdx.x;

#pragma unroll
  for (int it = 0; it < 4; ++it) {
    int idx = it * 256 + t;                 // 0..1023
    int c = idx >> 4, q = idx & 15;
    u16x8 v = {};
    if (hw0 + q * 8 < 4225)
      v = *(const u16x8*)(xfn + (size_t)(b * 256 + c0 + c) * PL + hw0 + q * 8);
#pragma unroll
    for (int k = 0; k < 8; ++k)
      ld[(q * 8 + k) * 66 + (c ^ (k << 3))] = v[k];
  }
  __syncthreads();
#pragma unroll
  for (int it = 0; it < 4; ++it) {
    int idx = it * 256 + t;
    int hwl = idx >> 3, a = idx & 7;
    int k7 = hwl & 7;
    int hw = hw0 + hwl;
    if (hw < 4225) {
      u16x8 v = *(const u16x8*)&ld[hwl * 66 + ((a ^ k7) << 3)];
      *(u16x8*)&xft[((size_t)(b * 4225 + hw) << 8) + c0 + (a << 3)] = v;
    }
  }
}

// ---------------- Kernel 3: implicit-conv GEMM, 128x128 tile, 64x64 waves -------
// C[oc=256][n=16384]; BM=128, BN=128, BK=64; 256 thr, 4 waves (2m x 2n) of 64x64.
// grid 256 = 1 block/CU. Double-buffered LDS (64 KB), counted vmcnt(8) pipeline.
// Per-wave per iter: 16 ds_read_b128 : 32 MFMA (512 B LDS per MFMA, was 750).
__global__ __launch_bounds__(256) void k_gemm3(const ushort* __restrict__ Wb,
                                               const ushort* __restrict__ Xt,
                                               const float* __restrict__ bias,
                                               float* __restrict__ out) {
  __shared__ ushort lA[2][128 * 64];               // 16 KB each
  __shared__ ushort lB[2][128 * 64];               // 16 KB each (64 KB total)
  const int bid = blockIdx.x;                      // 0..255
  const int work = (bid & 7) * 32 + (bid >> 3);    // XCD-chunked bijective (256%8==0)
  const int ntile = work >> 1;
  const int mtile = work & 1;
  const int m0 = mtile * 128;
  const int n0 = ntile * 128;
  const int t = threadIdx.x;
  const int wid = t >> 6, lane = t & 63;
  const int wm = wid >> 1, wn = wid & 1;
  const int lrow = lane & 15, kgrp = lane >> 4;

  // staging sources (pre-swizzled: lds 16B-chunk (idx&7) holds data chunk (idx&7)^(row&7))
  const ushort* aB[4];
#pragma unroll
  for (int i = 0; i < 4; ++i) {
    int idx = i * 256 + t;
    int row = idx >> 3;
    aB[i] = Wb + (size_t)(m0 + row) * KD + (((idx & 7) ^ (row & 7)) << 3);
  }
  const ushort* bB[4];
#pragma unroll
  for (int i = 0; i < 4; ++i) {
    int idx = i * 256 + t;
    int row = idx >> 3;
    int n = n0 + row;
    int b = n >> 10, oh = (n >> 5) & 31, ow = n & 31;
    bB[i] = Xt + ((size_t)((b * 65 + 2 * oh) * 65 + 2 * ow) << 8) +
            (((idx & 7) ^ (row & 7)) << 3);
  }

#define STAGE(buf, kt)                                                         \
  {                                                                            \
    const int j_ = (kt) >> 2;                                                  \
    const int dh_ = j_ / 3, dw_ = j_ - 3 * dh_;                                \
    const int boff_ = (dh_ * 65 + dw_) * 256 + (((kt) & 3) << 6);              \
    const int k0_ = (kt) << 6;                                                 \
    _Pragma("unroll") for (int i_ = 0; i_ < 4; ++i_)                           \
        GLDS16(aB[i_] + k0_, &lA[buf][(i_ * 256 + t) * 8]);                    \
    _Pragma("unroll") for (int i_ = 0; i_ < 4; ++i_)                           \
        GLDS16(bB[i_] + boff_, &lB[buf][(i_ * 256 + t) * 8]);                  \
  }

  // precomputed swizzled read addresses (LDS byte offsets), buf0
  unsigned aAddr[2][4], bAddr[2][4];
#pragma unroll
  for (int f = 0; f < 4; ++f) {
    int arow = wm * 64 + f * 16 + lrow;
    int brow = wn * 64 + f * 16 + lrow;
#pragma unroll
    for (int s = 0; s < 2; ++s) {
      aAddr[s][f] = LDSOFF(&lA[0][arow * 64 + (((s * 4 + kgrp) ^ arow) & 7) * 8]);
      bAddr[s][f] = LDSOFF(&lB[0][brow * 64 + (((s * 4 + kgrp) ^ brow) & 7) * 8]);
    }
  }

  f32x4 acc[4][4];
#pragma unroll
  for (int i = 0; i < 4; ++i)
#pragma unroll
    for (int j = 0; j < 4; ++j) acc[i][j] = (f32x4){0.f, 0.f, 0.f, 0.f};

  STAGE(0, 0);

  for (int kt = 0; kt < 36; ++kt) {
    const int cur = kt & 1;
    if (kt < 35) STAGE(cur ^ 1, kt + 1);

    if (kt < 35)
      asm volatile("s_waitcnt vmcnt(8)" ::: "memory");   // cur tile resident
    else
      asm volatile("s_waitcnt vmcnt(0)" ::: "memory");
    __builtin_amdgcn_s_barrier();
    __builtin_amdgcn_sched_barrier(0);

    const unsigned off = cur ? (unsigned)(128 * 64 * 2) : 0u;
#pragma unroll
    for (int s = 0; s < 2; ++s) {
      bf16x8 Af0, Af1, Af2, Af3, Bf0, Bf1, Bf2, Bf3;
      DSREAD(Af0, aAddr[s][0] + off);
      DSREAD(Af1, aAddr[s][1] + off);
      DSREAD(Af2, aAddr[s][2] + off);
      DSREAD(Af3, aAddr[s][3] + off);
      DSREAD(Bf0, bAddr[s][0] + off);
      DSREAD(Bf1, bAddr[s][1] + off);
      DSREAD(Bf2, bAddr[s][2] + off);
      DSREAD(Bf3, bAddr[s][3] + off);
      asm volatile("s_waitcnt lgkmcnt(0)" ::: "memory");
      __builtin_amdgcn_sched_barrier(0);
      acc[0][0] = __builtin_amdgcn_mfma_f32_16x16x32_bf16(Af0, Bf0, acc[0][0], 0, 0, 0);
      acc[0][1] = __builtin_amdgcn_mfma_f32_16x16x32_bf16(Af0, Bf1, acc[0][1], 0, 0, 0);
      acc[0][2] = __builtin_amdgcn_mfma_f32_16x16x32_bf16(Af0, Bf2, acc[0][2], 0, 0, 0);
      acc[0][3] = __builtin_amdgcn_mfma_f32_16x16x32_bf16(Af0, Bf3, acc[0][3], 0, 0, 0);
      acc[1][0] = __builtin_amdgcn_mfma_f32_16x16x32_bf16(Af1, Bf0, acc[1][0], 0, 0, 0);
      acc[1][1] = __builtin_amdgcn_mfma_f32_16x16x32_bf16(Af1, Bf1, acc[1][1], 0, 0, 0);
      acc[1][2] = __builtin_amdgcn_mfma_f32_16x16x32_bf16(Af1, Bf2, acc[1][2], 0, 0, 0);
      acc[1][3] = __builtin_amdgcn_mfma_f32_16x16x32_bf16(Af1, Bf3, acc[1][3], 0, 0, 0);
      acc[2][0] = __builtin_amdgcn_mfma_f32_16x16x32_bf16(Af2, Bf0, acc[2][0], 0, 0, 0);
      acc[2][1] = __builtin_amdgcn_mfma_f32_16x16x32_bf16(Af2, Bf1, acc[2][1], 0, 0, 0);
      acc[2][2] = __builtin_amdgcn_mfma_f32_16x16x32_bf16(Af2, Bf2, acc[2][2], 0, 0, 0);
      acc[2][3] = __builtin_amdgcn_mfma_f32_16x16x32_bf16(Af2, Bf3, acc[2][3], 0, 0, 0);
      acc[3][0] = __builtin_amdgcn_mfma_f32_16x16x32_bf16(Af3, Bf0, acc[3][0], 0, 0, 0);
      acc[3][1] = __builtin_amdgcn_mfma_f32_16x16x32_bf16(Af3, Bf1, acc[3][1], 0, 0, 0);
      acc[3][2] = __builtin_amdgcn_mfma_f32_16x16x32_bf16(Af3, Bf2, acc[3][2], 0, 0, 0);
      acc[3][3] = __builtin_amdgcn_mfma_f32_16x16x32_bf16(Af3, Bf3, acc[3][3], 0, 0, 0);
    }
    __builtin_amdgcn_sched_barrier(0);
    __builtin_amdgcn_s_barrier();     // all waves done reading cur before re-stage
  }

  f32x4 bv[4];
#pragma unroll
  for (int fm = 0; fm < 4; ++fm)
    bv[fm] = *(const f32x4*)(bias + m0 + wm * 64 + fm * 16 + kgrp * 4);

#pragma unroll
  for (int fm = 0; fm < 4; ++fm) {
#pragma unroll
    for (int fn = 0; fn < 4; ++fn) {
      int nn = n0 + wn * 64 + fn * 16 + lrow;
      int oc = m0 + wm * 64 + fm * 16 + kgrp * 4;
      float* op = out + (size_t)(nn >> 10) * OUT_PER_B + (nn & 1023) +
                  (size_t)oc * 1024;
      op[0]    = acc[fm][fn][0] + bv[fm][0];
      op[1024] = acc[fm][fn][1] + bv[fm][1];
      op[2048] = acc[fm][fn][2] + bv[fm][2];
      op[3072] = acc[fm][fn][3] + bv[fm][3];
    }
  }
}

extern "C" void kernel_launch(void* const* d_in, const int* in_sizes, int n_in,
                              void* d_out, int out_size, void* d_ws, size_t ws_size,
                              hipStream_t stream) {
  const float* x    = (const float*)d_in[0];  // [16,256,64,64]
  const float* w    = (const float*)d_in[1];  // [256,256,3,3]
  const float* bias = (const float*)d_in[2];  // [256]
  float* out = (float*)d_out;                 // [16,256,32,32]

  char* ws = (char*)d_ws;
  ushort* xfn = (ushort*)ws;                        // 4096*4232*2 = 34,668,544 B
  ushort* xft = (ushort*)(ws + 34668544);           // 16*4225*256*2 = 34,611,200 B
  ushort* wb  = (ushort*)(ws + 34668544 + 34611200);// 1,179,648 B

  k_fir<<<4096, 256, 0, stream>>>(x, xfn, w, wb);
  k_tr<<<dim3(34, 4, 16), 256, 0, stream>>>(xfn, xft);
  k_gemm3<<<256, 256, 0, stream>>>(wb, xft, bias, out);
}